// Round 2
// baseline (1618.930 us; speedup 1.0000x reference)
//
#include <hip/hip_runtime.h>

#define BB    32
#define CDIM  256
#define TT    2048
#define NE    1024
#define NROWS (BB * TT)          // 65536
#define NELEM (BB * CDIM * TT)   // 16777216

// dist_argmin tiling
#define RT 128                   // rows per block
#define CT 128                   // codes per chunk
#define KC 16                    // k's per LDS stage

// ---------------------------------------------------------------------------
// numpy pairwise sum of squares over 128 elements (stride in elements),
// replicating numpy's pairwise_sum: 8 partial accumulators, combined
// ((r0+r1)+(r2+r3)) + ((r4+r5)+(r6+r7)).  fp contract OFF.
// ---------------------------------------------------------------------------
__device__ __forceinline__ float np_sq_sum128(const float* p, int stride) {
#pragma clang fp contract(off)
  float r[8];
#pragma unroll
  for (int j = 0; j < 8; j++) {
    float v = p[(size_t)j * stride];
    r[j] = v * v;
  }
  for (int i = 8; i < 128; i += 8) {
#pragma unroll
    for (int j = 0; j < 8; j++) {
      float v = p[(size_t)(i + j) * stride];
      float s = v * v;
      r[j] += s;
    }
  }
  return ((r[0] + r[1]) + (r[2] + r[3])) + ((r[4] + r[5]) + (r[6] + r[7]));
}

__global__ __launch_bounds__(256) void e2_kernel(const float* __restrict__ cb,
                                                 float* __restrict__ e2) {
#pragma clang fp contract(off)
  int k = blockIdx.x * 256 + threadIdx.x;
  if (k >= NE) return;
  const float* p = cb + (size_t)k * CDIM;
  float h0 = np_sq_sum128(p, 1);
  float h1 = np_sq_sum128(p + 128, 1);
  e2[k] = h0 + h1;
}

__global__ __launch_bounds__(256) void z2_kernel(const float* __restrict__ z,
                                                 float* __restrict__ z2) {
#pragma clang fp contract(off)
  int n = blockIdx.x * 256 + threadIdx.x;
  if (n >= NROWS) return;
  int b = n >> 11;
  int t = n & (TT - 1);
  const float* p = z + (size_t)b * CDIM * TT + t;
  float h0 = np_sq_sum128(p, TT);
  float h1 = np_sq_sum128(p + (size_t)128 * TT, TT);
  z2[n] = h0 + h1;
}

// ---------------------------------------------------------------------------
// Distance + argmin, v2: 128 rows x 128 codes per block, 256 threads
// (16 tx codes x 16 ty rows), 8x8 accumulators per thread.  K staged 16
// at a time in LDS with register prefetch of the next stage during compute.
// Numerics identical to v1 (bit-exact vs np): per (row,code) the dot is a
// single fp32 accumulator, k = 0..255 sequential, mul-then-add (contract
// off); d = fl( fl(z2+e2) - fl(2*G) ); first-occurrence argmin.
// ---------------------------------------------------------------------------
__global__ __launch_bounds__(256, 2) void dist_argmin_kernel(
    const float* __restrict__ z, const float* __restrict__ cb,
    const float* __restrict__ z2, const float* __restrict__ e2,
    int* __restrict__ out_idx) {
#pragma clang fp contract(off)
  __shared__ float zs[KC][RT];       // 8 KiB  [k][row]
  __shared__ float es[KC][CT + 4];   // 8.25 KiB [k][code], pad keeps 16B align
  __shared__ float rv[RT][17];
  __shared__ int   ri[RT][17];

  const int bid = blockIdx.x;
  const int b   = bid >> 4;               // 16 row-tiles per batch
  const int t0  = (bid & 15) << 7;
  const int tid = threadIdx.x;
  const int tx  = tid & 15;               // code group
  const int ty  = tid >> 4;               // row group

  const float* zb = z + (size_t)b * CDIM * TT + t0;

  // staging coordinates
  const int st_t  = tid & 127;            // z: t within tile
  const int st_kh = tid >> 7;             // z: k half (0..1)
  const int st_c  = tid & 15;             // e: k within stage
  const int st_g  = tid >> 4;             // e: code group (0..15)

  float pf_z[8], pf_e[8];

  auto load_stage = [&](int s) {
    int n0 = (s >> 4) << 7;               // code chunk base
    int kc = (s & 15) << 4;               // k base
#pragma unroll
    for (int i = 0; i < 8; i++)
      pf_z[i] = zb[(size_t)(kc + st_kh * 8 + i) * TT + st_t];
#pragma unroll
    for (int i = 0; i < 8; i++)
      pf_e[i] = cb[(size_t)(n0 + st_g * 8 + i) * CDIM + kc + st_c];
  };

  float bv[8];
  int   bi[8];
#pragma unroll
  for (int r = 0; r < 8; r++) { bv[r] = __builtin_inff(); bi[r] = 0; }

  float z2r[8];
#pragma unroll
  for (int r = 0; r < 8; r++) z2r[r] = z2[b * TT + t0 + ty * 8 + r];

  float acc[8][8];

  load_stage(0);

  for (int s = 0; s < (NE / CT) * (CDIM / KC); s++) {   // 8 chunks x 16 stages
    __syncthreads();                       // prior stage's readers done
    {                                      // regs -> LDS
#pragma unroll
      for (int i = 0; i < 8; i++) zs[st_kh * 8 + i][st_t] = pf_z[i];
#pragma unroll
      for (int i = 0; i < 8; i++) es[st_c][st_g * 8 + i] = pf_e[i];
    }
    __syncthreads();

    if (s + 1 < (NE / CT) * (CDIM / KC)) load_stage(s + 1);  // overlaps compute

    if ((s & 15) == 0) {
#pragma unroll
      for (int r = 0; r < 8; r++)
#pragma unroll
        for (int j = 0; j < 8; j++) acc[r][j] = 0.0f;
    }

#pragma unroll
    for (int k = 0; k < KC; k++) {
      float za[8], ea[8];
      *(float4*)&za[0] = *(const float4*)&zs[k][ty * 8];
      *(float4*)&za[4] = *(const float4*)&zs[k][ty * 8 + 4];
      *(float4*)&ea[0] = *(const float4*)&es[k][tx * 8];
      *(float4*)&ea[4] = *(const float4*)&es[k][tx * 8 + 4];
#pragma unroll
      for (int r = 0; r < 8; r++)
#pragma unroll
        for (int j = 0; j < 8; j++) {
          float p = za[r] * ea[j];         // no FMA: match np mul-then-add
          acc[r][j] += p;
        }
    }

    if ((s & 15) == 15) {                  // chunk epilogue
      int n0 = (s >> 4) << 7;
#pragma unroll
      for (int j = 0; j < 8; j++) {
        int   code = n0 + tx * 8 + j;
        float e2c  = e2[code];
#pragma unroll
        for (int r = 0; r < 8; r++) {
          float tg = 2.0f * acc[r][j];
          float sv = z2r[r] + e2c;
          float d  = sv - tg;
          if (d < bv[r]) { bv[r] = d; bi[r] = code; }  // codes ascend
        }
      }
    }
  }

  __syncthreads();
#pragma unroll
  for (int r = 0; r < 8; r++) {
    rv[ty * 8 + r][tx] = bv[r];
    ri[ty * 8 + r][tx] = bi[r];
  }
  __syncthreads();
  if (tid < RT) {
    float v  = rv[tid][0];
    int   ii = ri[tid][0];
#pragma unroll
    for (int x = 1; x < 16; x++) {
      float v2 = rv[tid][x];
      int   i2 = ri[tid][x];
      if (v2 < v || (v2 == v && i2 < ii)) { v = v2; ii = i2; }
    }
    out_idx[b * TT + t0 + tid] = ii;
  }
}

// ---------------------------------------------------------------------------
// Gather z_q, straight-through output fl(z + fl(zq - z)), loss accumulation
// ---------------------------------------------------------------------------
__global__ __launch_bounds__(256) void zq_loss_kernel(
    const float* __restrict__ z, const float* __restrict__ cb,
    const int* __restrict__ idx, float* __restrict__ zq_out,
    double* __restrict__ loss_acc) {
#pragma clang fp contract(off)
  __shared__ double sh[256];
  double local = 0.0;
  int stride = gridDim.x * blockDim.x;
  for (int i = blockIdx.x * blockDim.x + threadIdx.x; i < NELEM; i += stride) {
    int t = i & (TT - 1);
    int b = i >> 19;
    int c = (i >> 11) & (CDIM - 1);
    int n = (b << 11) | t;
    float zq   = cb[(size_t)idx[n] * CDIM + c];
    float zv   = z[i];
    float diff = zq - zv;
    zq_out[i]  = zv + diff;
    float sq   = diff * diff;
    local += (double)sq;
  }
  sh[threadIdx.x] = local;
  __syncthreads();
  for (int s = 128; s > 0; s >>= 1) {
    if (threadIdx.x < s) sh[threadIdx.x] += sh[threadIdx.x + s];
    __syncthreads();
  }
  if (threadIdx.x == 0) atomicAdd(loss_acc, sh[0]);
}

// one-hot: write every element exactly once (replaces memset + scatter-touch)
// 4 rows per block, 64 threads/row, 4 float4 per thread
__global__ __launch_bounds__(256) void onehot_kernel(
    const int* __restrict__ idx, float* __restrict__ oh) {
  int row  = blockIdx.x * 4 + (threadIdx.x >> 6);
  int lane = threadIdx.x & 63;
  int k    = idx[row];
  float4* dst = (float4*)(oh + (size_t)row * NE);
#pragma unroll
  for (int i = 0; i < 4; i++) {
    int c4   = i * 64 + lane;            // float4 index 0..255, coalesced
    int base = c4 * 4;
    float4 v = {0.f, 0.f, 0.f, 0.f};
    if (k >= base && k < base + 4) ((float*)&v)[k - base] = 1.0f;
    dst[c4] = v;
  }
}

// indices output (as float) + histogram
__global__ __launch_bounds__(256) void scatter_kernel(
    const int* __restrict__ idx, float* __restrict__ idx_out,
    int* __restrict__ cnt) {
  int n = blockIdx.x * 256 + threadIdx.x;
  if (n >= NROWS) return;
  int k = idx[n];
  idx_out[n] = (float)k;
  atomicAdd(&cnt[k], 1);
}

__global__ __launch_bounds__(1024) void finalize_kernel(
    const int* __restrict__ cnt, const double* __restrict__ loss_acc,
    float* __restrict__ out_loss, float* __restrict__ out_perp) {
#pragma clang fp contract(off)
  __shared__ float sh[1024];
  int t = threadIdx.x;
  float em = (float)cnt[t] / 65536.0f;
  sh[t] = em * logf(em + 1e-10f);
  __syncthreads();
  for (int s = 512; s > 0; s >>= 1) {
    if (t < s) sh[t] += sh[t + s];
    __syncthreads();
  }
  if (t == 0) {
    *out_perp = expf(-sh[0]);
    double m  = *loss_acc / (double)NELEM;
    float mf  = (float)m;
    float bt  = 0.25f * mf;
    *out_loss = mf + bt;
  }
}

// ---------------------------------------------------------------------------
extern "C" void kernel_launch(void* const* d_in, const int* in_sizes, int n_in,
                              void* d_out, int out_size, void* d_ws,
                              size_t ws_size, hipStream_t stream) {
  const float* z  = (const float*)d_in[0];
  const float* cb = (const float*)d_in[1];
  float* out = (float*)d_out;

  // workspace layout
  int*    ws_idx  = (int*)d_ws;              // 65536 ints
  int*    ws_cnt  = ws_idx + NROWS;          // 1024 ints
  double* ws_loss = (double*)(ws_cnt + NE);  // 8-aligned
  float*  ws_e2   = (float*)(ws_loss + 1);   // 1024 floats
  float*  ws_z2   = ws_e2 + NE;              // 65536 floats

  // output layout (flat fp32 concat, reference return order)
  float* out_loss = out;
  float* out_zq   = out + 1;
  float* out_perp = out + 1 + (size_t)NELEM;
  float* out_oh   = out + 2 + (size_t)NELEM;
  float* out_idx  = out + 2 + (size_t)NELEM + (size_t)NROWS * NE;

  hipMemsetAsync(ws_cnt, 0, NE * sizeof(int) + sizeof(double), stream);

  e2_kernel<<<NE / 256, 256, 0, stream>>>(cb, ws_e2);
  z2_kernel<<<NROWS / 256, 256, 0, stream>>>(z, ws_z2);
  dist_argmin_kernel<<<NROWS / RT, 256, 0, stream>>>(z, cb, ws_z2, ws_e2,
                                                     ws_idx);
  zq_loss_kernel<<<2048, 256, 0, stream>>>(z, cb, ws_idx, out_zq, ws_loss);
  onehot_kernel<<<NROWS / 4, 256, 0, stream>>>(ws_idx, out_oh);
  scatter_kernel<<<NROWS / 256, 256, 0, stream>>>(ws_idx, out_idx, ws_cnt);
  finalize_kernel<<<1, 1024, 0, stream>>>(ws_cnt, ws_loss, out_loss, out_perp);
}

// Round 3
// 1315.447 us; speedup vs baseline: 1.2307x; 1.2307x over previous
//
#include <hip/hip_runtime.h>

#define BB    32
#define CDIM  256
#define TT    2048
#define NE    1024
#define NROWS (BB * TT)          // 65536
#define NELEM (BB * CDIM * TT)   // 16777216

// dist_argmin tiling
#define RT 128                   // rows per block
#define CT 128                   // codes per chunk
#define KC 32                    // k's per LDS stage
#define ESTRIDE 132              // es row stride (≡4 mod 32 → staggered banks)

// ---------------------------------------------------------------------------
// numpy pairwise sum of squares over 128 elements (stride in elements):
// 8 partial accumulators, combined ((r0+r1)+(r2+r3)) + ((r4+r5)+(r6+r7)).
// fp contract OFF (numpy squares then adds, no FMA).
// ---------------------------------------------------------------------------
__device__ __forceinline__ float np_sq_sum128(const float* p, int stride) {
#pragma clang fp contract(off)
  float r[8];
#pragma unroll
  for (int j = 0; j < 8; j++) {
    float v = p[(size_t)j * stride];
    r[j] = v * v;
  }
  for (int i = 8; i < 128; i += 8) {
#pragma unroll
    for (int j = 0; j < 8; j++) {
      float v = p[(size_t)(i + j) * stride];
      float s = v * v;
      r[j] += s;
    }
  }
  return ((r[0] + r[1]) + (r[2] + r[3])) + ((r[4] + r[5]) + (r[6] + r[7]));
}

__global__ __launch_bounds__(256) void e2_kernel(const float* __restrict__ cb,
                                                 float* __restrict__ e2) {
#pragma clang fp contract(off)
  int k = blockIdx.x * 256 + threadIdx.x;
  if (k >= NE) return;
  const float* p = cb + (size_t)k * CDIM;
  float h0 = np_sq_sum128(p, 1);
  float h1 = np_sq_sum128(p + 128, 1);
  e2[k] = h0 + h1;
}

__global__ __launch_bounds__(256) void z2_kernel(const float* __restrict__ z,
                                                 float* __restrict__ z2) {
#pragma clang fp contract(off)
  int n = blockIdx.x * 256 + threadIdx.x;
  if (n >= NROWS) return;
  int b = n >> 11;
  int t = n & (TT - 1);
  const float* p = z + (size_t)b * CDIM * TT + t;
  float h0 = np_sq_sum128(p, TT);
  float h1 = np_sq_sum128(p + (size_t)128 * TT, TT);
  z2[n] = h0 + h1;
}

// ---------------------------------------------------------------------------
// Distance + argmin, v3: 128 rows x 128-code chunks, 256 threads (16 tx x
// 16 ty), 8x8 accs with HALF-SPLIT tiles: thread (tx,ty) owns rows
// {ty*4+r, 64+ty*4+r} and codes {tx*4+j, 64+tx*4+j}.  All LDS b128 reads
// land on quads (k+tx) mod 8 / broadcast -> conflict-free.  No prefetch
// registers (multi-block overlap hides staging), no min-wave clamp.
// Numerics bit-exact vs np (proven round 1/2): per (row,code) one fp32
// accumulator, k = 0..255 sequential, mul-then-add (contract off);
// d = fl( fl(z2+e2) - fl(2*G) ); first-occurrence argmin.
// ---------------------------------------------------------------------------
struct StageMem {
  float zs[KC][RT];              // 16 KiB  [k][row], row quad-aligned
  float es[KC][ESTRIDE];         // 16.5 KiB [k][code], stride 132
};
struct RedMem {
  float rv[RT][17];
  int   ri[RT][17];
};

__global__ __launch_bounds__(256) void dist_argmin_kernel(
    const float* __restrict__ z, const float* __restrict__ cb,
    const float* __restrict__ z2, const float* __restrict__ e2,
    int* __restrict__ out_idx) {
#pragma clang fp contract(off)
  __shared__ union SMem {
    StageMem st;
    RedMem   rd;
  } sm;

  const int bid = blockIdx.x;
  const int b   = bid >> 4;               // 16 row-tiles per batch
  const int t0  = (bid & 15) << 7;
  const int tid = threadIdx.x;
  const int tx  = tid & 15;               // code group
  const int ty  = tid >> 4;               // row group

  const float* zb = z + (size_t)b * CDIM * TT + t0;

  // staging coordinates: 32 quads x 8 k-groups
  const int c4 = tid & 31;                // quad within 128-wide row
  const int kq = tid >> 5;                // 0..7

  float bv[8];
  int   bi[8];
#pragma unroll
  for (int r = 0; r < 8; r++) { bv[r] = __builtin_inff(); bi[r] = 0; }

  float z2r[8];
#pragma unroll
  for (int r = 0; r < 8; r++) {
    int row = (r < 4) ? (ty * 4 + r) : (64 + ty * 4 + (r - 4));
    z2r[r] = z2[b * TT + t0 + row];
  }

  for (int n0 = 0; n0 < NE; n0 += CT) {
    float acc[8][8];
#pragma unroll
    for (int r = 0; r < 8; r++)
#pragma unroll
      for (int j = 0; j < 8; j++) acc[r][j] = 0.0f;

    for (int kc = 0; kc < CDIM; kc += KC) {
      __syncthreads();                     // prior stage's readers done
      // stage z: 32 k x 128 t, float4 in / b128 out (coalesced, 8 lanes/quad)
#pragma unroll
      for (int h = 0; h < 4; h++) {
        int k = kq + 8 * h;
        float4 v = *(const float4*)(zb + (size_t)(kc + k) * TT + c4 * 4);
        *(float4*)&sm.st.zs[k][c4 * 4] = v;
      }
      // stage cb: 32 k x 128 codes, transposed gather -> b128 writes
#pragma unroll
      for (int h = 0; h < 4; h++) {
        int k = kq + 8 * h;
        float4 v;
        v.x = cb[(size_t)(n0 + c4 * 4 + 0) * CDIM + kc + k];
        v.y = cb[(size_t)(n0 + c4 * 4 + 1) * CDIM + kc + k];
        v.z = cb[(size_t)(n0 + c4 * 4 + 2) * CDIM + kc + k];
        v.w = cb[(size_t)(n0 + c4 * 4 + 3) * CDIM + kc + k];
        *(float4*)&sm.st.es[k][c4 * 4] = v;
      }
      __syncthreads();

#pragma unroll 4
      for (int k = 0; k < KC; k++) {
        float za[8], ea[8];
        *(float4*)&za[0] = *(const float4*)&sm.st.zs[k][ty * 4];
        *(float4*)&za[4] = *(const float4*)&sm.st.zs[k][64 + ty * 4];
        *(float4*)&ea[0] = *(const float4*)&sm.st.es[k][tx * 4];
        *(float4*)&ea[4] = *(const float4*)&sm.st.es[k][64 + tx * 4];
#pragma unroll
        for (int r = 0; r < 8; r++)
#pragma unroll
          for (int j = 0; j < 8; j++) {
            float p = za[r] * ea[j];       // no FMA: match np mul-then-add
            acc[r][j] += p;
          }
      }
    }

    // chunk epilogue: quantize like np, fold into running argmin
#pragma unroll
    for (int j = 0; j < 8; j++) {
      int   code = n0 + ((j < 4) ? (tx * 4 + j) : (64 + tx * 4 + (j - 4)));
      float e2c  = e2[code];
#pragma unroll
      for (int r = 0; r < 8; r++) {
        float tg = 2.0f * acc[r][j];
        float sv = z2r[r] + e2c;
        float d  = sv - tg;
        if (d < bv[r]) { bv[r] = d; bi[r] = code; }  // codes ascend in j,n0
      }
    }
  }

  __syncthreads();
#pragma unroll
  for (int r = 0; r < 8; r++) {
    int row = (r < 4) ? (ty * 4 + r) : (64 + ty * 4 + (r - 4));
    sm.rd.rv[row][tx] = bv[r];
    sm.rd.ri[row][tx] = bi[r];
  }
  __syncthreads();
  if (tid < RT) {
    float v  = sm.rd.rv[tid][0];
    int   ii = sm.rd.ri[tid][0];
#pragma unroll
    for (int x = 1; x < 16; x++) {
      float v2 = sm.rd.rv[tid][x];
      int   i2 = sm.rd.ri[tid][x];
      if (v2 < v || (v2 == v && i2 < ii)) { v = v2; ii = i2; }
    }
    out_idx[b * TT + t0 + tid] = ii;
  }
}

// ---------------------------------------------------------------------------
// Gather z_q, straight-through output fl(z + fl(zq - z)), loss accumulation
// ---------------------------------------------------------------------------
__global__ __launch_bounds__(256) void zq_loss_kernel(
    const float* __restrict__ z, const float* __restrict__ cb,
    const int* __restrict__ idx, float* __restrict__ zq_out,
    double* __restrict__ loss_acc) {
#pragma clang fp contract(off)
  __shared__ double sh[256];
  double local = 0.0;
  int stride = gridDim.x * blockDim.x;
  for (int i = blockIdx.x * blockDim.x + threadIdx.x; i < NELEM; i += stride) {
    int t = i & (TT - 1);
    int b = i >> 19;
    int c = (i >> 11) & (CDIM - 1);
    int n = (b << 11) | t;
    float zq   = cb[(size_t)idx[n] * CDIM + c];
    float zv   = z[i];
    float diff = zq - zv;
    zq_out[i]  = zv + diff;
    float sq   = diff * diff;
    local += (double)sq;
  }
  sh[threadIdx.x] = local;
  __syncthreads();
  for (int s = 128; s > 0; s >>= 1) {
    if (threadIdx.x < s) sh[threadIdx.x] += sh[threadIdx.x + s];
    __syncthreads();
  }
  if (threadIdx.x == 0) atomicAdd(loss_acc, sh[0]);
}

// one-hot (every element written once) + indices output + histogram
// 4 rows per block, 64 threads/row, 4 float4 per thread
__global__ __launch_bounds__(256) void onehot_kernel(
    const int* __restrict__ idx, float* __restrict__ oh,
    float* __restrict__ idx_out, int* __restrict__ cnt) {
  int row  = blockIdx.x * 4 + (threadIdx.x >> 6);
  int lane = threadIdx.x & 63;
  int k    = idx[row];
  if (lane == 0) {
    idx_out[row] = (float)k;
    atomicAdd(&cnt[k], 1);
  }
  float4* dst = (float4*)(oh + (size_t)row * NE);
#pragma unroll
  for (int i = 0; i < 4; i++) {
    int c4   = i * 64 + lane;            // float4 index 0..255, coalesced
    int base = c4 * 4;
    float4 v = {0.f, 0.f, 0.f, 0.f};
    if (k >= base && k < base + 4) ((float*)&v)[k - base] = 1.0f;
    dst[c4] = v;
  }
}

__global__ __launch_bounds__(1024) void finalize_kernel(
    const int* __restrict__ cnt, const double* __restrict__ loss_acc,
    float* __restrict__ out_loss, float* __restrict__ out_perp) {
#pragma clang fp contract(off)
  __shared__ float sh[1024];
  int t = threadIdx.x;
  float em = (float)cnt[t] / 65536.0f;
  sh[t] = em * logf(em + 1e-10f);
  __syncthreads();
  for (int s = 512; s > 0; s >>= 1) {
    if (t < s) sh[t] += sh[t + s];
    __syncthreads();
  }
  if (t == 0) {
    *out_perp = expf(-sh[0]);
    double m  = *loss_acc / (double)NELEM;
    float mf  = (float)m;
    float bt  = 0.25f * mf;
    *out_loss = mf + bt;
  }
}

// ---------------------------------------------------------------------------
extern "C" void kernel_launch(void* const* d_in, const int* in_sizes, int n_in,
                              void* d_out, int out_size, void* d_ws,
                              size_t ws_size, hipStream_t stream) {
  const float* z  = (const float*)d_in[0];
  const float* cb = (const float*)d_in[1];
  float* out = (float*)d_out;

  // workspace layout
  int*    ws_idx  = (int*)d_ws;              // 65536 ints
  int*    ws_cnt  = ws_idx + NROWS;          // 1024 ints
  double* ws_loss = (double*)(ws_cnt + NE);  // 8-aligned
  float*  ws_e2   = (float*)(ws_loss + 1);   // 1024 floats
  float*  ws_z2   = ws_e2 + NE;              // 65536 floats

  // output layout (flat fp32 concat, reference return order)
  float* out_loss = out;
  float* out_zq   = out + 1;
  float* out_perp = out + 1 + (size_t)NELEM;
  float* out_oh   = out + 2 + (size_t)NELEM;
  float* out_idx  = out + 2 + (size_t)NELEM + (size_t)NROWS * NE;

  hipMemsetAsync(ws_cnt, 0, NE * sizeof(int) + sizeof(double), stream);

  e2_kernel<<<NE / 256, 256, 0, stream>>>(cb, ws_e2);
  z2_kernel<<<NROWS / 256, 256, 0, stream>>>(z, ws_z2);
  dist_argmin_kernel<<<NROWS / RT, 256, 0, stream>>>(z, cb, ws_z2, ws_e2,
                                                     ws_idx);
  zq_loss_kernel<<<2048, 256, 0, stream>>>(z, cb, ws_idx, out_zq, ws_loss);
  onehot_kernel<<<NROWS / 4, 256, 0, stream>>>(ws_idx, out_oh, out_idx,
                                               ws_cnt);
  finalize_kernel<<<1, 1024, 0, stream>>>(ws_cnt, ws_loss, out_loss, out_perp);
}

// Round 4
// 1190.443 us; speedup vs baseline: 1.3599x; 1.1050x over previous
//
#include <hip/hip_runtime.h>

#define BB    32
#define CDIM  256
#define TT    2048
#define NE    1024
#define NROWS (BB * TT)          // 65536
#define NELEM (BB * CDIM * TT)   // 16777216

// dist_argmin tiling
#define RT 128                   // rows per block
#define CT 128                   // codes per chunk
#define KC 32                    // k's per LDS stage
#define NHALF 512                // codes per block (code-split factor 2)
#define ESTRIDE 132              // es row stride (≡4 mod 32)

typedef float v2f __attribute__((ext_vector_type(2)));

// ---------------------------------------------------------------------------
// numpy pairwise sum of squares over 128 elements (stride in elements):
// 8 partial accumulators, combined ((r0+r1)+(r2+r3)) + ((r4+r5)+(r6+r7)).
// fp contract OFF (numpy squares then adds, no FMA).
// ---------------------------------------------------------------------------
__device__ __forceinline__ float np_sq_sum128(const float* p, int stride) {
#pragma clang fp contract(off)
  float r[8];
#pragma unroll
  for (int j = 0; j < 8; j++) {
    float v = p[(size_t)j * stride];
    r[j] = v * v;
  }
  for (int i = 8; i < 128; i += 8) {
#pragma unroll
    for (int j = 0; j < 8; j++) {
      float v = p[(size_t)(i + j) * stride];
      float s = v * v;
      r[j] += s;
    }
  }
  return ((r[0] + r[1]) + (r[2] + r[3])) + ((r[4] + r[5]) + (r[6] + r[7]));
}

__global__ __launch_bounds__(256) void e2_kernel(const float* __restrict__ cb,
                                                 float* __restrict__ e2) {
#pragma clang fp contract(off)
  int k = blockIdx.x * 256 + threadIdx.x;
  if (k >= NE) return;
  const float* p = cb + (size_t)k * CDIM;
  float h0 = np_sq_sum128(p, 1);
  float h1 = np_sq_sum128(p + 128, 1);
  e2[k] = h0 + h1;
}

__global__ __launch_bounds__(256) void z2_kernel(const float* __restrict__ z,
                                                 float* __restrict__ z2) {
#pragma clang fp contract(off)
  int n = blockIdx.x * 256 + threadIdx.x;
  if (n >= NROWS) return;
  int b = n >> 11;
  int t = n & (TT - 1);
  const float* p = z + (size_t)b * CDIM * TT + t;
  float h0 = np_sq_sum128(p, TT);
  float h1 = np_sq_sum128(p + (size_t)128 * TT, TT);
  z2[n] = h0 + h1;
}

// ---------------------------------------------------------------------------
// Distance + argmin, v4: code-split across 2 blocks (grid 1024 = 4 blocks/CU)
// + float2-packed inner MAC (v_pk_mul/add_f32 candidates; per-component
// fp32 ops identical to scalar -> bit-exact).  Block: 128 rows x 512 codes,
// 256 threads (16 tx x 16 ty), 8x8 accs, half-split tiles.
// Numerics bit-exact vs np: per (row,code) one fp32 accumulator, k = 0..255
// sequential mul-then-add (contract off); d = fl( fl(z2+e2) - fl(2*G) );
// first-occurrence argmin (half0 wins ties in combine).
// ---------------------------------------------------------------------------
struct StageMem {
  float zs[KC][RT];              // 16 KiB  [k][row]
  float es[KC][ESTRIDE];         // 16.5 KiB [k][code]
};
struct RedMem {
  float rv[RT][17];
  int   ri[RT][17];
};

__global__ __launch_bounds__(256, 4) void dist_argmin_kernel(
    const float* __restrict__ z, const float* __restrict__ cb,
    const float* __restrict__ z2, const float* __restrict__ e2,
    float* __restrict__ pv, int* __restrict__ pi) {
#pragma clang fp contract(off)
  __shared__ union SMem {
    StageMem st;
    RedMem   rd;
  } sm;

  const int bid  = blockIdx.x;
  const int half = bid & 1;               // code half
  const int rt   = bid >> 1;              // row tile 0..511
  const int b    = rt >> 4;
  const int t0   = (rt & 15) << 7;
  const int n_base = half * NHALF;
  const int tid = threadIdx.x;
  const int tx  = tid & 15;               // code group
  const int ty  = tid >> 4;               // row group

  const float* zb = z + (size_t)b * CDIM * TT + t0;

  // staging coordinates: 32 quads x 8 k-groups
  const int c4 = tid & 31;
  const int kq = tid >> 5;

  float bv[8];
  int   bi[8];
#pragma unroll
  for (int r = 0; r < 8; r++) { bv[r] = __builtin_inff(); bi[r] = 0; }

  float z2r[8];
#pragma unroll
  for (int r = 0; r < 8; r++) {
    int row = (r < 4) ? (ty * 4 + r) : (64 + ty * 4 + (r - 4));
    z2r[r] = z2[b * TT + t0 + row];
  }

  for (int n0 = n_base; n0 < n_base + NHALF; n0 += CT) {
    v2f acc2[8][4];
#pragma unroll
    for (int r = 0; r < 8; r++)
#pragma unroll
      for (int j = 0; j < 4; j++) acc2[r][j] = (v2f){0.0f, 0.0f};

    for (int kc = 0; kc < CDIM; kc += KC) {
      __syncthreads();
      // stage z: 32 k x 128 t, float4 in / b128 out
#pragma unroll
      for (int h = 0; h < 4; h++) {
        int k = kq + 8 * h;
        float4 v = *(const float4*)(zb + (size_t)(kc + k) * TT + c4 * 4);
        *(float4*)&sm.st.zs[k][c4 * 4] = v;
      }
      // stage cb: 32 k x 128 codes, transposed gather -> b128 writes
#pragma unroll
      for (int h = 0; h < 4; h++) {
        int k = kq + 8 * h;
        float4 v;
        v.x = cb[(size_t)(n0 + c4 * 4 + 0) * CDIM + kc + k];
        v.y = cb[(size_t)(n0 + c4 * 4 + 1) * CDIM + kc + k];
        v.z = cb[(size_t)(n0 + c4 * 4 + 2) * CDIM + kc + k];
        v.w = cb[(size_t)(n0 + c4 * 4 + 3) * CDIM + kc + k];
        *(float4*)&sm.st.es[k][c4 * 4] = v;
      }
      __syncthreads();

#pragma unroll 4
      for (int k = 0; k < KC; k++) {
        float za[8];
        *(float4*)&za[0] = *(const float4*)&sm.st.zs[k][ty * 4];
        *(float4*)&za[4] = *(const float4*)&sm.st.zs[k][64 + ty * 4];
        float4 e0 = *(const float4*)&sm.st.es[k][tx * 4];
        float4 e1 = *(const float4*)&sm.st.es[k][64 + tx * 4];
        v2f ea2[4];
        ea2[0] = (v2f){e0.x, e0.y};
        ea2[1] = (v2f){e0.z, e0.w};
        ea2[2] = (v2f){e1.x, e1.y};
        ea2[3] = (v2f){e1.z, e1.w};
#pragma unroll
        for (int r = 0; r < 8; r++) {
          v2f zr = (v2f){za[r], za[r]};
#pragma unroll
          for (int j = 0; j < 4; j++) {
            v2f p = zr * ea2[j];           // packed mul (no FMA)
            acc2[r][j] += p;               // packed add
          }
        }
      }
    }

    // chunk epilogue: quantize like np, fold into running argmin
#pragma unroll
    for (int j = 0; j < 8; j++) {
      int   code = n0 + ((j < 4) ? (tx * 4 + j) : (64 + tx * 4 + (j - 4)));
      float e2c  = e2[code];
#pragma unroll
      for (int r = 0; r < 8; r++) {
        float a  = acc2[r][j >> 1][j & 1];
        float tg = 2.0f * a;
        float sv = z2r[r] + e2c;
        float d  = sv - tg;
        if (d < bv[r]) { bv[r] = d; bi[r] = code; }  // codes ascend in j,n0
      }
    }
  }

  __syncthreads();
#pragma unroll
  for (int r = 0; r < 8; r++) {
    int row = (r < 4) ? (ty * 4 + r) : (64 + ty * 4 + (r - 4));
    sm.rd.rv[row][tx] = bv[r];
    sm.rd.ri[row][tx] = bi[r];
  }
  __syncthreads();
  if (tid < RT) {
    float v  = sm.rd.rv[tid][0];
    int   ii = sm.rd.ri[tid][0];
#pragma unroll
    for (int x = 1; x < 16; x++) {
      float v2 = sm.rd.rv[tid][x];
      int   i2 = sm.rd.ri[tid][x];
      if (v2 < v || (v2 == v && i2 < ii)) { v = v2; ii = i2; }
    }
    int row = b * TT + t0 + tid;
    pv[half * NROWS + row] = v;
    pi[half * NROWS + row] = ii;
  }
}

// combine the two code-half candidates; half0 has lower indices -> wins ties
__global__ __launch_bounds__(256) void combine_kernel(
    const float* __restrict__ pv, const int* __restrict__ pi,
    int* __restrict__ out_idx) {
  int n = blockIdx.x * 256 + threadIdx.x;
  if (n >= NROWS) return;
  float v0 = pv[n], v1 = pv[NROWS + n];
  int   i0 = pi[n], i1 = pi[NROWS + n];
  out_idx[n] = (v1 < v0) ? i1 : i0;
}

// ---------------------------------------------------------------------------
// Gather z_q, straight-through output fl(z + fl(zq - z)), loss accumulation
// ---------------------------------------------------------------------------
__global__ __launch_bounds__(256) void zq_loss_kernel(
    const float* __restrict__ z, const float* __restrict__ cb,
    const int* __restrict__ idx, float* __restrict__ zq_out,
    double* __restrict__ loss_acc) {
#pragma clang fp contract(off)
  __shared__ double sh[256];
  double local = 0.0;
  int stride = gridDim.x * blockDim.x;
  for (int i = blockIdx.x * blockDim.x + threadIdx.x; i < NELEM; i += stride) {
    int t = i & (TT - 1);
    int b = i >> 19;
    int c = (i >> 11) & (CDIM - 1);
    int n = (b << 11) | t;
    float zq   = cb[(size_t)idx[n] * CDIM + c];
    float zv   = z[i];
    float diff = zq - zv;
    zq_out[i]  = zv + diff;
    float sq   = diff * diff;
    local += (double)sq;
  }
  sh[threadIdx.x] = local;
  __syncthreads();
  for (int s = 128; s > 0; s >>= 1) {
    if (threadIdx.x < s) sh[threadIdx.x] += sh[threadIdx.x + s];
    __syncthreads();
  }
  if (threadIdx.x == 0) atomicAdd(loss_acc, sh[0]);
}

// one-hot (every element written once) + indices output + histogram
__global__ __launch_bounds__(256) void onehot_kernel(
    const int* __restrict__ idx, float* __restrict__ oh,
    float* __restrict__ idx_out, int* __restrict__ cnt) {
  int row  = blockIdx.x * 4 + (threadIdx.x >> 6);
  int lane = threadIdx.x & 63;
  int k    = idx[row];
  if (lane == 0) {
    idx_out[row] = (float)k;
    atomicAdd(&cnt[k], 1);
  }
  float4* dst = (float4*)(oh + (size_t)row * NE);
#pragma unroll
  for (int i = 0; i < 4; i++) {
    int c4   = i * 64 + lane;
    int base = c4 * 4;
    float4 v = {0.f, 0.f, 0.f, 0.f};
    if (k >= base && k < base + 4) ((float*)&v)[k - base] = 1.0f;
    dst[c4] = v;
  }
}

__global__ __launch_bounds__(1024) void finalize_kernel(
    const int* __restrict__ cnt, const double* __restrict__ loss_acc,
    float* __restrict__ out_loss, float* __restrict__ out_perp) {
#pragma clang fp contract(off)
  __shared__ float sh[1024];
  int t = threadIdx.x;
  float em = (float)cnt[t] / 65536.0f;
  sh[t] = em * logf(em + 1e-10f);
  __syncthreads();
  for (int s = 512; s > 0; s >>= 1) {
    if (t < s) sh[t] += sh[t + s];
    __syncthreads();
  }
  if (t == 0) {
    *out_perp = expf(-sh[0]);
    double m  = *loss_acc / (double)NELEM;
    float mf  = (float)m;
    float bt  = 0.25f * mf;
    *out_loss = mf + bt;
  }
}

// ---------------------------------------------------------------------------
extern "C" void kernel_launch(void* const* d_in, const int* in_sizes, int n_in,
                              void* d_out, int out_size, void* d_ws,
                              size_t ws_size, hipStream_t stream) {
  const float* z  = (const float*)d_in[0];
  const float* cb = (const float*)d_in[1];
  float* out = (float*)d_out;

  // workspace layout
  int*    ws_idx  = (int*)d_ws;              // 65536 ints
  int*    ws_cnt  = ws_idx + NROWS;          // 1024 ints
  double* ws_loss = (double*)(ws_cnt + NE);  // 8-aligned
  float*  ws_e2   = (float*)(ws_loss + 1);   // 1024 floats
  float*  ws_z2   = ws_e2 + NE;              // 65536 floats
  float*  ws_pv   = ws_z2 + NROWS;           // 2*65536 floats
  int*    ws_pi   = (int*)(ws_pv + 2 * NROWS);  // 2*65536 ints

  // output layout (flat fp32 concat, reference return order)
  float* out_loss = out;
  float* out_zq   = out + 1;
  float* out_perp = out + 1 + (size_t)NELEM;
  float* out_oh   = out + 2 + (size_t)NELEM;
  float* out_idx  = out + 2 + (size_t)NELEM + (size_t)NROWS * NE;

  hipMemsetAsync(ws_cnt, 0, NE * sizeof(int) + sizeof(double), stream);

  e2_kernel<<<NE / 256, 256, 0, stream>>>(cb, ws_e2);
  z2_kernel<<<NROWS / 256, 256, 0, stream>>>(z, ws_z2);
  dist_argmin_kernel<<<(NROWS / RT) * 2, 256, 0, stream>>>(z, cb, ws_z2,
                                                           ws_e2, ws_pv, ws_pi);
  combine_kernel<<<NROWS / 256, 256, 0, stream>>>(ws_pv, ws_pi, ws_idx);
  zq_loss_kernel<<<2048, 256, 0, stream>>>(z, cb, ws_idx, out_zq, ws_loss);
  onehot_kernel<<<NROWS / 4, 256, 0, stream>>>(ws_idx, out_oh, out_idx,
                                               ws_cnt);
  finalize_kernel<<<1, 1024, 0, stream>>>(ws_cnt, ws_loss, out_loss, out_perp);
}